// Round 7
// baseline (117.574 us; speedup 1.0000x reference)
//
#include <hip/hip_runtime.h>
#include <hip/hip_bf16.h>

#define BATCH 4096
#define NTOT  8192
#define DIM   512
#define NBLK  2080

typedef __attribute__((ext_vector_type(8))) __bf16 bf16x8;
typedef __attribute__((ext_vector_type(4))) float  floatx4;

__device__ __forceinline__ unsigned short f2bf(float x) {
  union { float f; unsigned u; } v; v.f = x;
  unsigned r = v.u + 0x7fffu + ((v.u >> 16) & 1u);   // RNE
  return (unsigned short)(r >> 16);
}

#define ASYNC16(gp, lp)                                                        \
  __builtin_amdgcn_global_load_lds(                                            \
      (__attribute__((address_space(1))) void*)(gp),                           \
      (__attribute__((address_space(3))) void*)(lp), 16, 0, 0)

// ---------------------------------------------------------------- normalize
// One wave per row: read 512 fp32, rsqrt(sum sq), write 512 bf16.
// Blocks 0..31 also zero S; block 32 zeroes out[0] (loss accumulates into it).
__global__ __launch_bounds__(256) void nrm_kernel(const float* __restrict__ zi,
                                                  const float* __restrict__ zj,
                                                  ushort* __restrict__ zn,
                                                  float* __restrict__ S,
                                                  float* __restrict__ out) {
  if (blockIdx.x < 32) S[blockIdx.x * 256 + threadIdx.x] = 0.0f;
  if (blockIdx.x == 32 && threadIdx.x == 0) out[0] = 0.0f;
  const int row = blockIdx.x * 4 + (threadIdx.x >> 6);
  const int l   = threadIdx.x & 63;
  const float* src = (row < BATCH) ? (zi + (size_t)row * DIM)
                                   : (zj + (size_t)(row - BATCH) * DIM);
  const float4* s4 = (const float4*)src;
  float4 v0 = s4[l];
  float4 v1 = s4[l + 64];
  float ss = v0.x*v0.x + v0.y*v0.y + v0.z*v0.z + v0.w*v0.w
           + v1.x*v1.x + v1.y*v1.y + v1.z*v1.z + v1.w*v1.w;
  #pragma unroll
  for (int m = 1; m < 64; m <<= 1) ss += __shfl_xor(ss, m, 64);
  const float r = 1.0f / fmaxf(sqrtf(ss), 1e-12f);
  ushort4 o0, o1;
  o0.x = f2bf(v0.x * r); o0.y = f2bf(v0.y * r);
  o0.z = f2bf(v0.z * r); o0.w = f2bf(v0.w * r);
  o1.x = f2bf(v1.x * r); o1.y = f2bf(v1.y * r);
  o1.z = f2bf(v1.z * r); o1.w = f2bf(v1.w * r);
  ushort4* d4 = (ushort4*)(zn + (size_t)row * DIM);
  d4[l]      = o0;
  d4[l + 64] = o1;
}

// ---------------------------------------------------------------- main GEMM
// R5 shell (2-buffer LDS, one __syncthreads per K-iter, compiler-scheduled)
// with BK=64: 8 K-iterations instead of 16. Rationale (R6 post-mortem):
// occupancy is REGISTER-bound at 8 waves/CU (148 regs/wave > 128), so wave
// count is fixed; depth-2 prefetch was null (R6) -> stall is barrier-rate +
// lgkm amortization, attacked by doubling MFMA per synchronization
// (16 ds_read -> 32 MFMA per wave-iter). LDS 66 KB still allows the same
// 2 blocks/CU (reg-bound anyway), unlike m132's BK=128 occupancy loss.
// LDS layout per buffer: 128 rows x 8 slots x 16B; k-chunk kc of row r
// stored at slot kc ^ (r&7) -> 8 consecutive lanes hit 8 distinct slots =
// all 32 banks, zero conflicts, and the inverse XOR is applied on the
// pre-swizzled global source (global_load_lds dest must stay linear).
// Lessons still pinned:
//  - NO fused loss tail (+15us, R3/R4). Waves retire fire-and-forget.
//  - NO agent-scope ACQ_REL RMW (L2 invalidate storm, +25us, R1/R2).
//  - NO XCD swizzle (+-3us, wrong regime).  - NO sched_barrier pinning (R1).
__global__ __launch_bounds__(256) void simsum_kernel(const ushort* __restrict__ zn,
                                                     float* __restrict__ S,
                                                     float* __restrict__ P) {
  // triangle decode: u = bj*(bj+1)/2 + bi, bi <= bj < 64
  const int u = blockIdx.x;
  int bj = (int)((sqrtf(8.0f * (float)u + 1.0f) - 1.0f) * 0.5f);
  while ((bj + 1) * (bj + 2) / 2 <= u) ++bj;
  while (bj * (bj + 1) / 2 > u) --bj;
  const int bi = u - bj * (bj + 1) / 2;
  const bool diag = (bi == bj);
  const bool posb = (bj == bi + BATCH / 128);

  __shared__ __align__(16) ushort shA[2 * 8192];   // 2 buf x 128 rows x 64 k
  __shared__ __align__(16) ushort shB[2 * 8192];
  __shared__ float redR[2][128];
  __shared__ float redC[2][128];

  const int t    = threadIdx.x;
  const int w    = t >> 6;
  const int l    = t & 63;
  const int quad = l >> 4;
  const int lo   = l & 15;
  const int wm   = w >> 1;
  const int wn   = w & 1;
  const int tileRow = bi * 128;
  const int tileCol = bj * 128;

  // staging: thread (w,l) stages LDS chunks p = w*256 + m*64 + l, m=0..3,
  // per matrix per K-tile. chunk p -> row r = p>>3 = w*32 + m*8 + (l>>3),
  // slot s = l&7; content k-chunk kc = s ^ (r&7) = (l&7) ^ (l>>3).
  const int lr = l >> 3;                 // r&7 contribution
  const int kc = (l & 7) ^ lr;           // source k-chunk for this lane
  const ushort* gA = zn + (size_t)(tileRow + w * 32 + lr) * DIM + kc * 8;
  const ushort* gB = zn + (size_t)(tileCol + w * 32 + lr) * DIM + kc * 8;
  ushort* lA = shA + w * 2048;           // chunk base w*256 -> ushort w*2048
  ushort* lB = shB + w * 2048;

  floatx4 acc[4][4];
  #pragma unroll
  for (int i = 0; i < 4; ++i)
    #pragma unroll
    for (int j = 0; j < 4; ++j)
      acc[i][j] = (floatx4){0.f, 0.f, 0.f, 0.f};

  // fragment reads: row = (wm|wn)*64 + i*16 + lo (row stride 64 ushorts);
  // lane (quad) needs k-chunk kk*4+quad, stored at slot (kk*4+quad)^(lo&7).
  const int s0 = (quad ^ (l & 7)) * 8;         // kk=0 slot (ushorts)
  const int s1 = ((4 + quad) ^ (l & 7)) * 8;   // kk=1 slot
  const int aRow = (wm * 64 + lo) * 64;        // + i*1024
  const int bRow = (wn * 64 + lo) * 64;        // + j*1024

  #define STAGE(bufo)                                                         \
    ASYNC16(gA,         lA + (bufo));                                         \
    ASYNC16(gA +  4096, lA + (bufo) + 512);                                   \
    ASYNC16(gA +  8192, lA + (bufo) + 1024);                                  \
    ASYNC16(gA + 12288, lA + (bufo) + 1536);                                  \
    ASYNC16(gB,         lB + (bufo));                                         \
    ASYNC16(gB +  4096, lB + (bufo) + 512);                                   \
    ASYNC16(gB +  8192, lB + (bufo) + 1024);                                  \
    ASYNC16(gB + 12288, lB + (bufo) + 1536);                                  \
    gA += 64; gB += 64;

  // prologue: stage K-tile 0 into buffer 0
  STAGE(0)

  #pragma unroll
  for (int it = 0; it < 8; ++it) {
    __syncthreads();  // drains loads for buffer `cur` (issued one iter ago)
    const int co = (it & 1) * 8192;
    const int no = co ^ 8192;
    if (it < 7) { STAGE(no) }
    bf16x8 aF[4][2], bF[4][2];
    #pragma unroll
    for (int i = 0; i < 4; ++i) {
      aF[i][0] = *(const bf16x8*)(shA + co + aRow + i * 1024 + s0);
      aF[i][1] = *(const bf16x8*)(shA + co + aRow + i * 1024 + s1);
    }
    #pragma unroll
    for (int j = 0; j < 4; ++j) {
      bF[j][0] = *(const bf16x8*)(shB + co + bRow + j * 1024 + s0);
      bF[j][1] = *(const bf16x8*)(shB + co + bRow + j * 1024 + s1);
    }
    #pragma unroll
    for (int i = 0; i < 4; ++i)
      #pragma unroll
      for (int j = 0; j < 4; ++j) {
        acc[i][j] = __builtin_amdgcn_mfma_f32_16x16x32_bf16(aF[i][0], bF[j][0],
                                                            acc[i][j], 0, 0, 0);
        acc[i][j] = __builtin_amdgcn_mfma_f32_16x16x32_bf16(aF[i][1], bF[j][1],
                                                            acc[i][j], 0, 0, 0);
      }
  }
  #undef STAGE

  // ---- epilogue. C/D layout: col = lo, row = quad*4 + r (within 16x16)
  float rs[4][4];
  float cs[4];
  #pragma unroll
  for (int i = 0; i < 4; ++i)
    #pragma unroll
    for (int r = 0; r < 4; ++r) rs[i][r] = 0.f;
  #pragma unroll
  for (int j = 0; j < 4; ++j) cs[j] = 0.f;

  #pragma unroll
  for (int i = 0; i < 4; ++i)
    #pragma unroll
    for (int j = 0; j < 4; ++j)
      #pragma unroll
      for (int r = 0; r < 4; ++r) {
        const float e = __expf(acc[i][j][r] * 10.0f - 10.0f);
        rs[i][r] += e;
        cs[j] += e;
      }

  // block-local diagonal lanes: wm==wn, lo == quad*4 + r  (i.e. quad == lo>>2)
  if (wm == wn && quad == (lo >> 2)) {
    const int r = lo & 3;
    if (diag) {  // self-similarity: remove exp from both row and col sums
      #pragma unroll
      for (int i = 0; i < 4; ++i) {
        const float e = __expf(acc[i][i][r] * 10.0f - 10.0f);
        rs[i][r] -= e;
        cs[i] -= e;
      }
    }
    if (posb) {  // positives: col == row + BATCH
      #pragma unroll
      for (int i = 0; i < 4; ++i) {
        const int row = tileRow + wm * 64 + i * 16 + lo;
        const float v = acc[i][i][r] * 10.0f;
        P[row] = v;
        P[row + BATCH] = v;
      }
    }
  }

  // row sums: reduce across the 16 column-lanes (low 4 lane bits)
  #pragma unroll
  for (int m = 1; m < 16; m <<= 1) {
    #pragma unroll
    for (int i = 0; i < 4; ++i)
      #pragma unroll
      for (int r = 0; r < 4; ++r)
        rs[i][r] += __shfl_xor(rs[i][r], m, 64);
  }
  if (lo == 0) {
    #pragma unroll
    for (int i = 0; i < 4; ++i)
      #pragma unroll
      for (int r = 0; r < 4; ++r)
        redR[wn][wm * 64 + i * 16 + quad * 4 + r] = rs[i][r];
  }
  // col sums: reduce across the 4 quads (lane bits 4,5)
  #pragma unroll
  for (int m = 16; m < 64; m <<= 1) {
    #pragma unroll
    for (int j = 0; j < 4; ++j) cs[j] += __shfl_xor(cs[j], m, 64);
  }
  if (quad == 0) {
    #pragma unroll
    for (int j = 0; j < 4; ++j)
      redC[wm][wn * 64 + j * 16 + lo] = cs[j];
  }
  __syncthreads();
  if (t < 128) {
    atomicAdd(&S[tileRow + t], redR[0][t] + redR[1][t]);
  } else if (!diag) {
    const int c = t - 128;
    atomicAdd(&S[tileCol + c], redC[0][c] + redC[1][c]);
  }
  // waves retire here, fire-and-forget on the atomics (no drain — critical).
}

// ---------------------------------------------------------------- final loss
// 32 blocks x 256 threads, 1 element/thread; partial per block, one float
// atomicAdd into out[0] (zeroed by nrm).
__global__ __launch_bounds__(256) void loss_kernel(const float* __restrict__ S,
                                                   const float* __restrict__ P,
                                                   float* __restrict__ out) {
  const int i = blockIdx.x * 256 + threadIdx.x;
  float a = 10.0f + logf(S[i]) - P[i];
  #pragma unroll
  for (int m = 1; m < 64; m <<= 1) a += __shfl_xor(a, m, 64);
  __shared__ float sb[4];
  if ((threadIdx.x & 63) == 0) sb[threadIdx.x >> 6] = a;
  __syncthreads();
  if (threadIdx.x == 0)
    atomicAdd(out, (sb[0] + sb[1] + sb[2] + sb[3]) * (1.0f / (float)NTOT));
}

extern "C" void kernel_launch(void* const* d_in, const int* in_sizes, int n_in,
                              void* d_out, int out_size, void* d_ws, size_t ws_size,
                              hipStream_t stream) {
  const float* zi = (const float*)d_in[0];
  const float* zj = (const float*)d_in[1];
  ushort* zn = (ushort*)d_ws;                                  // 8192*512 bf16 = 8 MB
  float*  S  = (float*)((char*)d_ws + (size_t)NTOT * DIM * 2); // 32 KB
  float*  P  = S + NTOT;                                       // 32 KB
  float*  out = (float*)d_out;

  nrm_kernel<<<NTOT / 4, 256, 0, stream>>>(zi, zj, zn, S, out);
  simsum_kernel<<<NBLK, 256, 0, stream>>>(zn, S, P);
  loss_kernel<<<NTOT / 256, 256, 0, stream>>>(S, P, out);
}